// Round 5
// baseline (175.805 us; speedup 1.0000x reference)
//
#include <hip/hip_runtime.h>

namespace {
constexpr int IMG_W = 512, IMG_H = 512;
constexpr int TW = 32, TH = 32;
constexpr int IN_W = TW + 10, IN_H = TH + 10;   // 42
constexpr int S12_STR = 46;  // float2 units; phase-2 b128 reads land minimally (8 dw/bank)
constexpr float C1c = 0.01f * 0.01f;
constexpr float C2c = 0.03f * 0.03f;

constexpr float GW[11] = {
    1.0283799e-03f, 7.5987582e-03f, 3.6000773e-02f, 1.0936069e-01f,
    2.1300554e-01f, 2.6601172e-01f, 2.1300554e-01f, 1.0936069e-01f,
    3.6000773e-02f, 7.5987582e-03f, 1.0283799e-03f
};

using v2f = __attribute__((ext_vector_type(2))) float;
using v4f = __attribute__((ext_vector_type(4))) float;

// Packed fp32 FMA with the weight in an SGPR pair (VOP3P scalar-64 source):
// compiler hoists the s_mov pair out of the loops; no per-tap v_mov.
__device__ __forceinline__ v2f pkfma_s(v2f w, v2f a, v2f c) {
    v2f d;
    asm("v_pk_fma_f32 %0, %1, %2, %3" : "=v"(d) : "s"(w), "v"(a), "v"(c));
    return d;
}
__device__ __forceinline__ v2f pkmul(v2f a, v2f b) {
    v2f d;
    asm("v_pk_mul_f32 %0, %1, %2" : "=v"(d) : "v"(a), "v"(b));
    return d;
}
__device__ __forceinline__ v2f bcast(float w) { v2f r; r.x = w; r.y = w; return r; }

// h-planes: stride 32 + rotate swizzle (col+row)&31 -> conflict-minimal both ways
__device__ __forceinline__ int hidx(int row, int col) {
    return row * 32 + ((col + row) & 31);
}
}

// LDS: union(s12 15456 B, h4 21504 + hab 5376 = 26880 B) + wred -> 27136 B alloc
// = 6 blocks/CU (27306 B budget), 24 waves/CU.
__global__ __launch_bounds__(256, 6) void ssim_tile_kernel(
        const float* __restrict__ img1, const float* __restrict__ img2,
        double* __restrict__ acc)
{
    union SharedU {
        v2f s12[IN_H * S12_STR];                // 15456 B
        struct {
            v4f   h4 [IN_H * 32];               // 21504 B (mu1,mu2,Exx,Eyy) swizzled
            float hab[IN_H * 32];               //  5376 B (Exy) swizzled
        } h;
    };
    __shared__ SharedU u;
    __shared__ float wred[4];

    const int tid = threadIdx.x;
    const size_t base = (size_t)blockIdx.z * (IMG_W * IMG_H);
    const float* p1 = img1 + base;
    const float* p2 = img2 + base;
    const int x0 = blockIdx.x * TW - 5;
    const int y0 = blockIdx.y * TH - 5;

    // ---- Phase 1: global -> LDS; interior blocks skip bounds checks ----
    if (blockIdx.x > 0 && blockIdx.x < gridDim.x - 1 &&
        blockIdx.y > 0 && blockIdx.y < gridDim.y - 1) {
#pragma unroll
        for (int i = 0; i < 7; ++i) {
            const int p = tid + i * 256;
            if (p < IN_H * IN_W) {
                const int r = p / IN_W, c = p - r * IN_W;
                const int off = (y0 + r) * IMG_W + (x0 + c);
                v2f t; t.x = p1[off]; t.y = p2[off];
                u.s12[r * S12_STR + c] = t;
            }
        }
    } else {
#pragma unroll
        for (int i = 0; i < 7; ++i) {
            const int p = tid + i * 256;
            if (p < IN_H * IN_W) {
                const int r = p / IN_W, c = p - r * IN_W;
                const int gy = y0 + r, gx = x0 + c;
                v2f t; t.x = 0.f; t.y = 0.f;
                if (gy >= 0 && gy < IMG_H && gx >= 0 && gx < IMG_W) {
                    const int off = gy * IMG_W + gx;
                    t.x = p1[off]; t.y = p2[off];
                }
                u.s12[r * S12_STR + c] = t;
            }
        }
    }
    __syncthreads();

    // ---- Phase 2: horizontal 11-tap, scatter form (taps outer, acc live) ----
    // 42 rows x 4 col-groups x 8 outputs = 168 active threads
    const int r2 = tid >> 2;
    const int cb = (tid & 3) * 8;
    v2f mu8[8], sq8[8];
    float xy8[8];
    if (tid < 168) {
#pragma unroll
        for (int j = 0; j < 8; ++j) {
            mu8[j] = bcast(0.f); sq8[j] = bcast(0.f); xy8[j] = 0.f;
        }
        const v4f* srow = (const v4f*)&u.s12[r2 * S12_STR + cb];
#pragma unroll
        for (int m = 0; m < 9; ++m) {
            const v4f q = srow[m];
#pragma unroll
            for (int half = 0; half < 2; ++half) {
                const int k = 2 * m + half;
                v2f v;
                v.x = half ? q.z : q.x;
                v.y = half ? q.w : q.y;
                const v2f a2 = pkmul(v, v);
                const float xyv = v.x * v.y;
#pragma unroll
                for (int j = 0; j < 8; ++j) {
                    const int t = k - j;
                    if (t >= 0 && t < 11) {
                        const v2f w2 = bcast(GW[t]);
                        mu8[j] = pkfma_s(w2, v,  mu8[j]);
                        sq8[j] = pkfma_s(w2, a2, sq8[j]);
                        xy8[j] = fmaf(GW[t], xyv, xy8[j]);
                    }
                }
            }
        }
    }
    __syncthreads();            // all reads of s12 done; safe to overwrite
    if (tid < 168) {
#pragma unroll
        for (int j = 0; j < 8; ++j) {
            const int idx = hidx(r2, cb + j);
            v4f q;
            q.x = mu8[j].x; q.y = mu8[j].y;
            q.z = sq8[j].x; q.w = sq8[j].y;
            u.h.h4 [idx] = q;
            u.h.hab[idx] = xy8[j];
        }
    }
    __syncthreads();

    // ---- Phase 3: vertical 11-tap + SSIM, scatter form, 4 rows/thread ----
    const int c  = tid & 31;
    const int rb = (tid >> 5) * 4;
    v2f mu4[4], sg4[4];
    float xy4[4];
#pragma unroll
    for (int j = 0; j < 4; ++j) {
        mu4[j] = bcast(0.f); sg4[j] = bcast(0.f); xy4[j] = 0.f;
    }
#pragma unroll
    for (int k = 0; k < 14; ++k) {
        const int idx = hidx(rb + k, c);
        const v4f q = u.h.h4[idx];
        const float hx = u.h.hab[idx];
        v2f hm; hm.x = q.x; hm.y = q.y;
        v2f hs; hs.x = q.z; hs.y = q.w;
#pragma unroll
        for (int j = 0; j < 4; ++j) {
            const int t = k - j;
            if (t >= 0 && t < 11) {
                const v2f w2 = bcast(GW[t]);
                mu4[j] = pkfma_s(w2, hm, mu4[j]);
                sg4[j] = pkfma_s(w2, hs, sg4[j]);
                xy4[j] = fmaf(GW[t], hx, xy4[j]);
            }
        }
    }
    float lsum = 0.f;
#pragma unroll
    for (int j = 0; j < 4; ++j) {
        const float mu1s = mu4[j].x * mu4[j].x;
        const float mu2s = mu4[j].y * mu4[j].y;
        const float mu12 = mu4[j].x * mu4[j].y;
        const float s1 = sg4[j].x - mu1s, s2 = sg4[j].y - mu2s, s12v = xy4[j] - mu12;
        const float num = (2.f * mu12 + C1c) * (2.f * s12v + C2c);
        const float den = (mu1s + mu2s + C1c) * (s1 + s2 + C2c);
        lsum += __fdividef(num, den);
    }

    // ---- Phase 4: block reduce -> double atomic into 256 ws slots ----
#pragma unroll
    for (int off = 32; off > 0; off >>= 1)
        lsum += __shfl_down(lsum, off, 64);
    if ((tid & 63) == 0) wred[tid >> 6] = lsum;
    __syncthreads();
    if (tid == 0) {
        const int bid = (blockIdx.z * gridDim.y + blockIdx.y) * gridDim.x + blockIdx.x;
        unsafeAtomicAdd(&acc[bid & 255],
                        (double)(wred[0] + wred[1] + wred[2] + wred[3]));
    }
}

__global__ __launch_bounds__(256) void ssim_final_kernel(
        const double* __restrict__ acc, float* __restrict__ out, double inv_total)
{
    const int tid = threadIdx.x;
    double a = acc[tid];
#pragma unroll
    for (int off = 32; off > 0; off >>= 1)
        a += __shfl_down(a, off, 64);
    __shared__ double ws[4];
    if ((tid & 63) == 0) ws[tid >> 6] = a;
    __syncthreads();
    if (tid == 0)
        out[0] = (float)((ws[0] + ws[1] + ws[2] + ws[3]) * inv_total);
}

extern "C" void kernel_launch(void* const* d_in, const int* in_sizes, int n_in,
                              void* d_out, int out_size, void* d_ws, size_t ws_size,
                              hipStream_t stream)
{
    const float* img1 = (const float*)d_in[0];
    const float* img2 = (const float*)d_in[1];
    double* acc = (double*)d_ws;

    hipMemsetAsync(d_ws, 0, 256 * sizeof(double), stream);

    const int nch = in_sizes[0] / (IMG_W * IMG_H);      // 16*3 = 48
    dim3 grid(IMG_W / TW, IMG_H / TH, nch);             // 16 x 16 x 48
    ssim_tile_kernel<<<grid, 256, 0, stream>>>(img1, img2, acc);

    const double inv_total = 1.0 / (double)in_sizes[0];
    ssim_final_kernel<<<1, 256, 0, stream>>>(acc, (float*)d_out, inv_total);
}

// Round 6
// 165.787 us; speedup vs baseline: 1.0604x; 1.0604x over previous
//
#include <hip/hip_runtime.h>

namespace {
constexpr int IMG_W = 512, IMG_H = 512;
constexpr int TW = 32, TH = 32;
constexpr int IN_W = TW + 10, IN_H = TH + 10;   // 42
constexpr int S12_STR = 46;  // float2 units; phase-2 b128 reads bank-minimal
constexpr float C1c = 0.01f * 0.01f;
constexpr float C2c = 0.03f * 0.03f;

constexpr float GW[11] = {
    1.0283799e-03f, 7.5987582e-03f, 3.6000773e-02f, 1.0936069e-01f,
    2.1300554e-01f, 2.6601172e-01f, 2.1300554e-01f, 1.0936069e-01f,
    3.6000773e-02f, 7.5987582e-03f, 1.0283799e-03f
};
constexpr float GWZ(int t) { return (t >= 0 && t < 11) ? GW[t] : 0.f; }

using v2f = __attribute__((ext_vector_type(2))) float;
using v4f = __attribute__((ext_vector_type(4))) float;

// In-place packed FMA, weight in SGPR pair: acc += w * a. Tied "+v" kills
// any result-copy movs; "s" hoists weight pairs to s_mov outside the loops.
__device__ __forceinline__ void pkfma(v2f& acc, v2f w, v2f a) {
    asm("v_pk_fma_f32 %0, %1, %2, %0" : "+v"(acc) : "s"(w), "v"(a));
}
__device__ __forceinline__ v2f pkmul(v2f a, v2f b) {
    v2f d;
    asm("v_pk_mul_f32 %0, %1, %2" : "=v"(d) : "v"(a), "v"(b));
    return d;
}
__device__ __forceinline__ v2f bcast(float w) { v2f r; r.x = w; r.y = w; return r; }

// h-planes: stride 32 + rotate swizzle (col+row)&31 (27136 B total with s12 union)
__device__ __forceinline__ int hidx(int row, int col) {
    return row * 32 + ((col + row) & 31);
}
}

__global__ __launch_bounds__(256, 6) void ssim_tile_kernel(
        const float* __restrict__ img1, const float* __restrict__ img2,
        double* __restrict__ acc)
{
    union SharedU {
        v2f s12[IN_H * S12_STR];                // 15456 B
        struct {
            v4f   h4 [IN_H * 32];               // 21504 B (mu1,mu2,Exx,Eyy) swizzled
            float hab[IN_H * 32];               //  5376 B (Exy) swizzled
        } h;
    };
    __shared__ SharedU u;
    __shared__ float wred[4];

    const int tid = threadIdx.x;
    const size_t base = (size_t)blockIdx.z * (IMG_W * IMG_H);
    const float* p1 = img1 + base;
    const float* p2 = img2 + base;
    const int x0 = blockIdx.x * TW - 5;
    const int y0 = blockIdx.y * TH - 5;

    // ---- Phase 1: global -> LDS, incremental addressing ----
    {
        int r = tid / IN_W;                 // magic-mul once
        int c = tid - r * IN_W;
        int goff = (y0 + r) * IMG_W + (x0 + c);
        int loff = r * S12_STR + c;
        const bool interior =
            blockIdx.x > 0 && blockIdx.x < gridDim.x - 1 &&
            blockIdx.y > 0 && blockIdx.y < gridDim.y - 1;
        if (interior) {
#pragma unroll
            for (int i = 0; i < 7; ++i) {
                if (i < 6 || tid < IN_H * IN_W - 6 * 256) {   // 228
                    v2f t; t.x = p1[goff]; t.y = p2[goff];
                    u.s12[loff] = t;
                }
                const bool wrap = (c + 4) >= IN_W;
                c    += wrap ? 4 - IN_W : 4;
                goff += wrap ? 7 * IMG_W - (IN_W - 4) : 6 * IMG_W + 4;
                loff += wrap ? 7 * S12_STR - (IN_W - 4) : 6 * S12_STR + 4;
                r    += wrap ? 7 : 6;
            }
        } else {
#pragma unroll
            for (int i = 0; i < 7; ++i) {
                if (i < 6 || tid < IN_H * IN_W - 6 * 256) {
                    const int gy = y0 + r, gx = x0 + c;
                    v2f t; t.x = 0.f; t.y = 0.f;
                    if (gy >= 0 && gy < IMG_H && gx >= 0 && gx < IMG_W) {
                        t.x = p1[goff]; t.y = p2[goff];
                    }
                    u.s12[loff] = t;
                }
                const bool wrap = (c + 4) >= IN_W;
                c    += wrap ? 4 - IN_W : 4;
                goff += wrap ? 7 * IMG_W - (IN_W - 4) : 6 * IMG_W + 4;
                loff += wrap ? 7 * S12_STR - (IN_W - 4) : 6 * S12_STR + 4;
                r    += wrap ? 7 : 6;
            }
        }
    }
    __syncthreads();

    // ---- Phase 2: horizontal 11-tap, scatter form, packed xy ----
    // 42 rows x 4 col-groups x 8 outputs = 168 active threads
    const int r2 = tid >> 2;
    const int cb = (tid & 3) * 8;
    v2f mu8[8], sq8[8], xy2[4];     // xy2[p] = {xy_{2p}, xy_{2p+1}}
    if (tid < 168) {
#pragma unroll
        for (int j = 0; j < 8; ++j) { mu8[j] = bcast(0.f); sq8[j] = bcast(0.f); }
#pragma unroll
        for (int p = 0; p < 4; ++p) xy2[p] = bcast(0.f);
        const v4f* srow = (const v4f*)&u.s12[r2 * S12_STR + cb];
#pragma unroll
        for (int m = 0; m < 9; ++m) {
            const v4f q = srow[m];
#pragma unroll
            for (int half = 0; half < 2; ++half) {
                const int k = 2 * m + half;
                v2f v;
                v.x = half ? q.z : q.x;
                v.y = half ? q.w : q.y;
                const v2f a2 = pkmul(v, v);
                v2f xyd;                       // {x*y, x*y}
                xyd.x = v.x * v.y;
                xyd.y = xyd.x;
#pragma unroll
                for (int j = 0; j < 8; ++j) {
                    const int t = k - j;
                    if (t >= 0 && t < 11) {
                        const v2f w2 = bcast(GW[t]);
                        pkfma(mu8[j], w2, v);
                        pkfma(sq8[j], w2, a2);
                    }
                }
#pragma unroll
                for (int p = 0; p < 4; ++p) {
                    const int t = k - 2 * p;
                    if (t >= 0 && t <= 11) {
                        v2f wp; wp.x = GWZ(t); wp.y = GWZ(t - 1);
                        pkfma(xy2[p], wp, xyd);
                    }
                }
            }
        }
    }
    __syncthreads();            // all reads of s12 done; safe to overwrite
    if (tid < 168) {
#pragma unroll
        for (int j = 0; j < 8; ++j) {
            const int idx = hidx(r2, cb + j);
            v4f q;
            q.x = mu8[j].x; q.y = mu8[j].y;
            q.z = sq8[j].x; q.w = sq8[j].y;
            u.h.h4 [idx] = q;
            u.h.hab[idx] = (j & 1) ? xy2[j >> 1].y : xy2[j >> 1].x;
        }
    }
    __syncthreads();

    // ---- Phase 3: vertical 11-tap + SSIM, scatter form, 4 rows/thread ----
    const int c  = tid & 31;
    const int rb = (tid >> 5) * 4;
    v2f mu4[4], sg4[4];
    float xy4[4];
#pragma unroll
    for (int j = 0; j < 4; ++j) {
        mu4[j] = bcast(0.f); sg4[j] = bcast(0.f); xy4[j] = 0.f;
    }
#pragma unroll
    for (int k = 0; k < 14; ++k) {
        const int idx = hidx(rb + k, c);
        const v4f q = u.h.h4[idx];
        const float hx = u.h.hab[idx];
        v2f hm; hm.x = q.x; hm.y = q.y;
        v2f hs; hs.x = q.z; hs.y = q.w;
#pragma unroll
        for (int j = 0; j < 4; ++j) {
            const int t = k - j;
            if (t >= 0 && t < 11) {
                const v2f w2 = bcast(GW[t]);
                pkfma(mu4[j], w2, hm);
                pkfma(sg4[j], w2, hs);
                xy4[j] = fmaf(GW[t], hx, xy4[j]);
            }
        }
    }
    float lsum = 0.f;
#pragma unroll
    for (int j = 0; j < 4; ++j) {
        const v2f musq = pkmul(mu4[j], mu4[j]);      // {mu1^2, mu2^2}
        const float mu12 = mu4[j].x * mu4[j].y;
        const float s1 = sg4[j].x - musq.x, s2 = sg4[j].y - musq.y;
        const float s12v = xy4[j] - mu12;
        const float num = (2.f * mu12 + C1c) * (2.f * s12v + C2c);
        const float den = (musq.x + musq.y + C1c) * (s1 + s2 + C2c);
        lsum += __fdividef(num, den);
    }

    // ---- Phase 4: block reduce -> double atomic into 256 ws slots ----
#pragma unroll
    for (int off = 32; off > 0; off >>= 1)
        lsum += __shfl_down(lsum, off, 64);
    if ((tid & 63) == 0) wred[tid >> 6] = lsum;
    __syncthreads();
    if (tid == 0) {
        const int bid = (blockIdx.z * gridDim.y + blockIdx.y) * gridDim.x + blockIdx.x;
        unsafeAtomicAdd(&acc[bid & 255],
                        (double)(wred[0] + wred[1] + wred[2] + wred[3]));
    }
}

__global__ __launch_bounds__(256) void ssim_final_kernel(
        const double* __restrict__ acc, float* __restrict__ out, double inv_total)
{
    const int tid = threadIdx.x;
    double a = acc[tid];
#pragma unroll
    for (int off = 32; off > 0; off >>= 1)
        a += __shfl_down(a, off, 64);
    __shared__ double ws[4];
    if ((tid & 63) == 0) ws[tid >> 6] = a;
    __syncthreads();
    if (tid == 0)
        out[0] = (float)((ws[0] + ws[1] + ws[2] + ws[3]) * inv_total);
}

extern "C" void kernel_launch(void* const* d_in, const int* in_sizes, int n_in,
                              void* d_out, int out_size, void* d_ws, size_t ws_size,
                              hipStream_t stream)
{
    const float* img1 = (const float*)d_in[0];
    const float* img2 = (const float*)d_in[1];
    double* acc = (double*)d_ws;

    hipMemsetAsync(d_ws, 0, 256 * sizeof(double), stream);

    const int nch = in_sizes[0] / (IMG_W * IMG_H);      // 16*3 = 48
    dim3 grid(IMG_W / TW, IMG_H / TH, nch);             // 16 x 16 x 48
    ssim_tile_kernel<<<grid, 256, 0, stream>>>(img1, img2, acc);

    const double inv_total = 1.0 / (double)in_sizes[0];
    ssim_final_kernel<<<1, 256, 0, stream>>>(acc, (float*)d_out, inv_total);
}